// Round 3
// baseline (255.519 us; speedup 1.0000x reference)
//
#include <hip/hip_runtime.h>
#include <hip/hip_cooperative_groups.h>

namespace cg = cooperative_groups;

typedef _Float16 f16;
typedef __attribute__((ext_vector_type(8))) _Float16 f16x8;
typedef __attribute__((ext_vector_type(4))) _Float16 f16x4;
typedef __attribute__((ext_vector_type(4))) float f32x4;

#define BAR() asm volatile("s_waitcnt lgkmcnt(0)\n\ts_barrier" ::: "memory")
#define VMDRAIN() asm volatile("s_waitcnt vmcnt(0)" ::: "memory")

namespace {
constexpr int kL   = 65536;
constexpr int kR   = 256;
constexpr int kD   = 64;
constexpr int kDV  = 64;

constexpr float kAc  = 0.1f;
constexpr float kBc  = 0.7745966692414834f;      // sqrt(0.6)
constexpr float kDnS = 0.2888816545234944f;      // 0.6^16 * 2^10 (PHI_SCALE folded)
constexpr float kOutScale = 9.5367431640625e-7f; // 2^-20 undoes PHI_SCALE^2
constexpr int kKvtOff = 6291456;                 // f16 elems = byte offset 12 MiB into d_out
}

// One cooperative kernel, 256 blocks x 512 threads (1 block/CU).
// P1: partials[blk][r*64+dv] (f16, d_out[0..8.4MB)) = phi(K_blkcols) @ V_blkcols
// P2: kvT[dv][r] (f16, d_out+12MB) = sum over 256 partial slices
// P3: out[l][dv] = phi(Q)^T @ kv
__global__ __launch_bounds__(512, 2)
void favor_fused(const float* __restrict__ Qg, const float* __restrict__ Kg,
                 const float* __restrict__ Vg, const float* __restrict__ Wg,
                 float* __restrict__ outg)
{
    __shared__ f16 sXt[64 * 64];    // K/Q chunk [l][d], swizzled (8 KB)
    __shared__ f16 sVt[64 * 64];    // V chunk [dv][l], swizzled (8 KB, P1 only)
    __shared__ f16 sPhi[256 * 64];  // P1: [r][l]; P3: [l][r] (32 KB)
    __shared__ float sRed[8 * 64];  // column-norm / reduce scratch (2 KB)

    const int tid  = threadIdx.x;
    const int w    = tid >> 6;
    const int lane = tid & 63;
    const int l15  = lane & 15;
    const int lhi  = lane >> 4;
    const int blk  = blockIdx.x;
    const int lblk = blk * 256;

    const int scol  = lane;     // staging column
    const int dbase = w * 8;    // staging row-group

    f16* partials = (f16*)outg;            // 256 slices x 16384 f16 = 8.39 MB
    f16* kvT      = (f16*)outg + kKvtOff;  // [dv][r] f16, 32 KB

    cg::grid_group grid = cg::this_grid();

    // ---- W fragments, loaded once, reused in P1 and P3.
    // A-frag (16x16x32): row = lane&15, k = 8*(lane>>4)+j (+32*ks)
    f16x8 wfrag[2][2];
#pragma unroll
    for (int ri = 0; ri < 2; ++ri)
#pragma unroll
        for (int ks = 0; ks < 2; ++ks) {
            const float* p = Wg + (32 * w + 16 * ri + l15) * kD + 32 * ks + 8 * lhi;
            f16x8 v;
#pragma unroll
            for (int j = 0; j < 8; ++j) v[j] = (f16)p[j];
            wfrag[ri][ks] = v;
        }

    // ======================= P1: partial KV =======================
    {
        const int wr = w >> 1;   // stage-2 r group (64 rows)
        const int wc = w & 1;    // stage-2 dv half (32 cols)

        f32x4 acc[4][2];
#pragma unroll
        for (int a = 0; a < 4; ++a)
#pragma unroll
            for (int d = 0; d < 2; ++d) { f32x4 z0 = {0.f, 0.f, 0.f, 0.f}; acc[a][d] = z0; }

        float kb[2][8], vb[2][8];
#pragma unroll
        for (int j = 0; j < 8; ++j) {
            kb[0][j] = Kg[(dbase + j) * kL + lblk + scol];
            vb[0][j] = Vg[(size_t)(lblk + dbase + j) * kDV + scol];
        }

#pragma unroll
        for (int t = 0; t < 4; ++t) {
            const int cur = t & 1;
            if (t < 3) {
                const int l1 = lblk + (t + 1) * 64;
#pragma unroll
                for (int j = 0; j < 8; ++j) {
                    kb[cur ^ 1][j] = Kg[(dbase + j) * kL + l1 + scol];
                    vb[cur ^ 1][j] = Vg[(size_t)(l1 + dbase + j) * kDV + scol];
                }
            }
            // stage current chunk from regs -> LDS (+ column-norm partials)
            {
                float s = 0.f;
                f16x8 hk, hv;
#pragma unroll
                for (int j = 0; j < 8; ++j) {
                    const float x = kb[cur][j];
                    s += x * x;
                    hk[j] = (f16)x;
                    hv[j] = (f16)vb[cur][j];
                }
                sRed[w * 64 + scol] = s;
                *(f16x8*)&sXt[scol * 64 + (dbase ^ ((scol & 7) << 3))] = hk;
                *(f16x8*)&sVt[scol * 64 + (dbase ^ ((scol & 7) << 3))] = hv;
            }
            BAR();

            float sqv = 0.f;
#pragma unroll
            for (int g = 0; g < 8; ++g) sqv += sRed[g * 64 + lane];
            float sqs[4];
#pragma unroll
            for (int lf = 0; lf < 4; ++lf) sqs[lf] = __shfl(sqv, lf * 16 + l15, 64);

            // Z = W @ K_chunk
            f32x4 z[2][4];
#pragma unroll
            for (int ri = 0; ri < 2; ++ri)
#pragma unroll
                for (int lf = 0; lf < 4; ++lf) { f32x4 z0 = {0.f, 0.f, 0.f, 0.f}; z[ri][lf] = z0; }
#pragma unroll
            for (int ks = 0; ks < 2; ++ks) {
                f16x8 bfr[4];
#pragma unroll
                for (int lf = 0; lf < 4; ++lf) {
                    const int row = 16 * lf + l15;
                    bfr[lf] = *(const f16x8*)&sXt[row * 64 + ((32 * ks + 8 * lhi) ^ ((row & 7) << 3))];
                }
#pragma unroll
                for (int ri = 0; ri < 2; ++ri)
#pragma unroll
                    for (int lf = 0; lf < 4; ++lf)
                        z[ri][lf] = __builtin_amdgcn_mfma_f32_16x16x32_f16(wfrag[ri][ks], bfr[lf], z[ri][lf], 0, 0, 0);
            }

            // phi -> sPhi [r][l]
#pragma unroll
            for (int ri = 0; ri < 2; ++ri) {
                const int rb = 32 * w + 16 * ri + 4 * lhi;
#pragma unroll
                for (int lf = 0; lf < 4; ++lf) {
                    const int lc = 16 * lf + l15;
#pragma unroll
                    for (int j = 0; j < 4; ++j) {
                        const float ph = kDnS * __expf(kAc + kBc * z[ri][lf][j] - sqs[lf]);
                        const int r = rb + j;
                        sPhi[r * 64 + (lc ^ ((r & 7) << 3))] = (f16)ph;
                    }
                }
            }
            BAR();

            // acc += phi @ V
#pragma unroll
            for (int ks = 0; ks < 2; ++ks) {
                f16x8 af[4], bf[2];
#pragma unroll
                for (int ai = 0; ai < 4; ++ai) {
                    const int r = 64 * wr + 16 * ai + l15;
                    af[ai] = *(const f16x8*)&sPhi[r * 64 + ((32 * ks + 8 * lhi) ^ ((r & 7) << 3))];
                }
#pragma unroll
                for (int di = 0; di < 2; ++di) {
                    const int dv = 32 * wc + 16 * di + l15;
                    bf[di] = *(const f16x8*)&sVt[dv * 64 + ((32 * ks + 8 * lhi) ^ ((dv & 7) << 3))];
                }
#pragma unroll
                for (int ai = 0; ai < 4; ++ai)
#pragma unroll
                    for (int di = 0; di < 2; ++di)
                        acc[ai][di] = __builtin_amdgcn_mfma_f32_16x16x32_f16(af[ai], bf[di], acc[ai][di], 0, 0, 0);
            }
            BAR();
        }

        // per-block partial KV, f16
        f16* po = partials + (size_t)blk * (kR * kDV);
#pragma unroll
        for (int ai = 0; ai < 4; ++ai)
#pragma unroll
            for (int di = 0; di < 2; ++di) {
                const int dv = 32 * wc + 16 * di + l15;
#pragma unroll
                for (int j = 0; j < 4; ++j) {
                    const int r = 64 * wr + 16 * ai + 4 * lhi + j;
                    po[r * kDV + dv] = (f16)acc[ai][di][j];
                }
            }
    }

    VMDRAIN();
    __threadfence();
    grid.sync();  // S1: all partials written

    // ======================= P2: reduce to kvT =======================
    {
        const f16* pb = partials + (size_t)(w * 32) * (kR * kDV) + blk * 64 + lane;
        float s = 0.f;
#pragma unroll 8
        for (int k2 = 0; k2 < 32; ++k2) s += (float)pb[(size_t)k2 * (kR * kDV)];
        sRed[w * 64 + lane] = s;
        __syncthreads();
        if (tid < 64) {
            float tot = 0.f;
#pragma unroll
            for (int g = 0; g < 8; ++g) tot += sRed[g * 64 + tid];
            kvT[tid * kR + blk] = (f16)tot;  // [dv][r], r = blk
        }
    }

    // prefetch Q chunk 0 while syncing
    float qb[2][8];
#pragma unroll
    for (int j = 0; j < 8; ++j) qb[0][j] = Qg[(dbase + j) * kL + lblk + scol];

    VMDRAIN();
    __threadfence();
    grid.sync();  // S3: kvT visible to all blocks

    // ======================= P3: out = phiQ^T @ kv =======================
    {
        const int dvh = w & 1;
        const int lfo = w >> 1;

        // kv B-fragments in registers: rows dv, cols r
        f16x8 kvf[2][8];
#pragma unroll
        for (int di = 0; di < 2; ++di) {
            const int dvr = 32 * dvh + 16 * di + l15;
#pragma unroll
            for (int ks = 0; ks < 8; ++ks)
                kvf[di][ks] = *(const f16x8*)&kvT[dvr * kR + 32 * ks + 8 * lhi];
        }

        VMDRAIN();
        __threadfence();
        grid.sync();  // S4: every block holds kv before any out store clobbers it

#pragma unroll
        for (int t = 0; t < 4; ++t) {
            const int cur = t & 1;
            const int l0 = lblk + t * 64;
            if (t < 3) {
#pragma unroll
                for (int j = 0; j < 8; ++j)
                    qb[cur ^ 1][j] = Qg[(dbase + j) * kL + (l0 + 64) + scol];
            }
            {
                float s = 0.f;
                f16x8 hq;
#pragma unroll
                for (int j = 0; j < 8; ++j) {
                    const float x = qb[cur][j];
                    s += x * x;
                    hq[j] = (f16)x;
                }
                sRed[w * 64 + scol] = s;
                *(f16x8*)&sXt[scol * 64 + (dbase ^ ((scol & 7) << 3))] = hq;
            }
            BAR();

            float sqv = 0.f;
#pragma unroll
            for (int g = 0; g < 8; ++g) sqv += sRed[g * 64 + lane];
            float sqs[4];
#pragma unroll
            for (int lf = 0; lf < 4; ++lf) sqs[lf] = __shfl(sqv, lf * 16 + l15, 64);

            f32x4 z[2][4];
#pragma unroll
            for (int ri = 0; ri < 2; ++ri)
#pragma unroll
                for (int lf = 0; lf < 4; ++lf) { f32x4 z0 = {0.f, 0.f, 0.f, 0.f}; z[ri][lf] = z0; }
#pragma unroll
            for (int ks = 0; ks < 2; ++ks) {
                f16x8 bfr[4];
#pragma unroll
                for (int lf = 0; lf < 4; ++lf) {
                    const int row = 16 * lf + l15;
                    bfr[lf] = *(const f16x8*)&sXt[row * 64 + ((32 * ks + 8 * lhi) ^ ((row & 7) << 3))];
                }
#pragma unroll
                for (int ri = 0; ri < 2; ++ri)
#pragma unroll
                    for (int lf = 0; lf < 4; ++lf)
                        z[ri][lf] = __builtin_amdgcn_mfma_f32_16x16x32_f16(wfrag[ri][ks], bfr[lf], z[ri][lf], 0, 0, 0);
            }

            // phi -> sPhi as [l][r], f16x4-packed
#pragma unroll
            for (int ri = 0; ri < 2; ++ri) {
                const int r0q = 32 * w + 16 * ri + 4 * lhi;
#pragma unroll
                for (int lf = 0; lf < 4; ++lf) {
                    const int lc = 16 * lf + l15;
                    f16x4 ph;
#pragma unroll
                    for (int j = 0; j < 4; ++j)
                        ph[j] = (f16)(kDnS * __expf(kAc + kBc * z[ri][lf][j] - sqs[lf]));
                    *(f16x4*)&sPhi[lc * 256 + (r0q ^ ((lc & 7) << 3))] = ph;
                }
            }
            BAR();

            // out tile: A = phiQ rows l, B = kv rows dv (in regs), K = 256 r
            f32x4 o2[2];
            { f32x4 z0 = {0.f, 0.f, 0.f, 0.f}; o2[0] = z0; o2[1] = z0; }
            const int lrow = 16 * lfo + l15;
#pragma unroll
            for (int ks = 0; ks < 8; ++ks) {
                f16x8 af = *(const f16x8*)&sPhi[lrow * 256 + ((32 * ks + 8 * lhi) ^ ((lrow & 7) << 3))];
#pragma unroll
                for (int di = 0; di < 2; ++di)
                    o2[di] = __builtin_amdgcn_mfma_f32_16x16x32_f16(af, kvf[di][ks], o2[di], 0, 0, 0);
            }
#pragma unroll
            for (int di = 0; di < 2; ++di)
#pragma unroll
                for (int j = 0; j < 4; ++j) {
                    const int ll = 16 * lfo + 4 * lhi + j;
                    const int dv = 32 * dvh + 16 * di + l15;
                    outg[(size_t)(l0 + ll) * kDV + dv] = o2[di][j] * kOutScale;
                }
            BAR();
        }
    }
}

extern "C" void kernel_launch(void* const* d_in, const int* in_sizes, int n_in,
                              void* d_out, int out_size, void* d_ws, size_t ws_size,
                              hipStream_t stream)
{
    const float* Q = (const float*)d_in[0];
    const float* K = (const float*)d_in[1];
    const float* V = (const float*)d_in[2];
    const float* W = (const float*)d_in[3];
    float* out = (float*)d_out;

    void* kargs[] = {(void*)&Q, (void*)&K, (void*)&V, (void*)&W, (void*)&out};
    hipLaunchCooperativeKernel((const void*)favor_fused, dim3(256), dim3(512),
                               kargs, 0, stream);

    (void)in_sizes; (void)n_in; (void)out_size; (void)d_ws; (void)ws_size;
}

// Round 4
// 53.632 us; speedup vs baseline: 4.7643x; 4.7643x over previous
//
#include <hip/hip_runtime.h>

typedef _Float16 f16;
typedef __attribute__((ext_vector_type(8))) _Float16 f16x8;
typedef __attribute__((ext_vector_type(4))) _Float16 f16x4;
typedef __attribute__((ext_vector_type(4))) float f32x4;

namespace {
constexpr int kL   = 65536;
constexpr int kR   = 256;
constexpr int kD   = 64;
constexpr int kDV  = 64;

constexpr int kABlocks = 512;   // 128 cols each (2 chunks of 64)
constexpr int kAChunks = 2;
constexpr int kBBlocks = 1024;  // 64 cols each

constexpr float kAc  = 0.1f;
constexpr float kBc  = 0.7745966692414834f;      // sqrt(0.6)
constexpr float kDnS = 0.2888816545234944f;      // 0.6^16 * 2^10 (PHI_SCALE folded)
constexpr float kOutScale = 9.5367431640625e-7f; // 2^-20 undoes PHI_SCALE^2
}

// ---------------------------------------------------------------------------
// Kernel A: partials[blk][dv][r] (f16) = (phi(K_cols)*2^10 @ V_cols)^T
// Swapped-operand MFMA for phi so each lane owns 4 consecutive l -> b64 stores.
// ---------------------------------------------------------------------------
__global__ __launch_bounds__(512, 2)
void favor_kv(const float* __restrict__ Kg, const float* __restrict__ Vg,
              const float* __restrict__ Wg, f16* __restrict__ partials)
{
    __shared__ f16 sXt[64 * 64];    // K chunk [l][d], swizzled
    __shared__ f16 sVt[64 * 64];    // V chunk [dv][l], swizzled
    __shared__ f16 sPhi[256 * 64];  // [r][l], swizzled
    __shared__ float sRed[8 * 64];  // per-wave norm partials
    __shared__ float sRedT[64];     // total column norms

    const int tid  = threadIdx.x;
    const int w    = tid >> 6;
    const int lane = tid & 63;
    const int l15  = lane & 15;
    const int lhi  = lane >> 4;
    const int blk  = blockIdx.x;
    const int lblk = blk * (64 * kAChunks);

    // W fragments; used as the B-operand (col = l15 -> r, k = 8*lhi+j -> d).
    f16x8 wfrag[2][2];
#pragma unroll
    for (int ri = 0; ri < 2; ++ri)
#pragma unroll
        for (int ks = 0; ks < 2; ++ks) {
            const float* p = Wg + (32 * w + 16 * ri + l15) * kD + 32 * ks + 8 * lhi;
            f16x8 v;
#pragma unroll
            for (int j = 0; j < 8; ++j) v[j] = (f16)p[j];
            wfrag[ri][ks] = v;
        }

    f32x4 acc[4][2];
#pragma unroll
    for (int a = 0; a < 4; ++a)
#pragma unroll
        for (int d = 0; d < 2; ++d) { f32x4 z0 = {0.f, 0.f, 0.f, 0.f}; acc[a][d] = z0; }

    const int wr = w >> 1;     // PV r-group (64 rows)
    const int wc = w & 1;      // PV dv half (32 cols)
    const int scol  = lane;
    const int dbase = w * 8;

    for (int t = 0; t < kAChunks; ++t) {
        const int l0 = lblk + t * 64;

        // ---- stage K,V (f32 -> f16, transposed, swizzled) + norm partials
        {
            float s = 0.f;
            f16x8 hk, hv;
#pragma unroll
            for (int j = 0; j < 8; ++j) {
                const float x = Kg[(dbase + j) * kL + l0 + scol];
                s += x * x;
                hk[j] = (f16)x;
            }
#pragma unroll
            for (int j = 0; j < 8; ++j)
                hv[j] = (f16)Vg[(size_t)(l0 + dbase + j) * kDV + scol];
            sRed[w * 64 + scol] = s;
            *(f16x8*)&sXt[scol * 64 + (dbase ^ ((scol & 7) << 3))] = hk;
            *(f16x8*)&sVt[scol * 64 + (dbase ^ ((scol & 7) << 3))] = hv;
        }
        __syncthreads();

        // column norms; every wave computes + writes identical sRedT (benign)
        {
            float sqv = 0.f;
#pragma unroll
            for (int g = 0; g < 8; ++g) sqv += sRed[g * 64 + lane];
            sRedT[lane] = sqv;
        }

        // ---- z = K^T W^T per ri: C[l][r]; then phi packed along l
#pragma unroll
        for (int ri = 0; ri < 2; ++ri) {
            f32x4 z[4];
#pragma unroll
            for (int lf = 0; lf < 4; ++lf) { f32x4 z0 = {0.f, 0.f, 0.f, 0.f}; z[lf] = z0; }
#pragma unroll
            for (int ks = 0; ks < 2; ++ks) {
                f16x8 bfr[4];
#pragma unroll
                for (int lf = 0; lf < 4; ++lf) {
                    const int row = 16 * lf + l15;
                    bfr[lf] = *(const f16x8*)&sXt[row * 64 + ((32 * ks + 8 * lhi) ^ ((row & 7) << 3))];
                }
#pragma unroll
                for (int lf = 0; lf < 4; ++lf)
                    z[lf] = __builtin_amdgcn_mfma_f32_16x16x32_f16(bfr[lf], wfrag[ri][ks], z[lf], 0, 0, 0);
            }
            const int r = 32 * w + 16 * ri + l15;
#pragma unroll
            for (int lf = 0; lf < 4; ++lf) {
                const f32x4 sq4 = *(const f32x4*)&sRedT[16 * lf + 4 * lhi];
                f16x4 ph;
#pragma unroll
                for (int j = 0; j < 4; ++j)
                    ph[j] = (f16)(kDnS * __expf(kAc + kBc * z[lf][j] - sq4[j]));
                const int lbase = 16 * lf + 4 * lhi;
                *(f16x4*)&sPhi[r * 64 + (lbase ^ ((r & 7) << 3))] = ph;
            }
        }
        __syncthreads();

        // ---- acc += phi @ V
#pragma unroll
        for (int ks = 0; ks < 2; ++ks) {
            f16x8 af[4], bf[2];
#pragma unroll
            for (int ai = 0; ai < 4; ++ai) {
                const int r = 64 * wr + 16 * ai + l15;
                af[ai] = *(const f16x8*)&sPhi[r * 64 + ((32 * ks + 8 * lhi) ^ ((r & 7) << 3))];
            }
#pragma unroll
            for (int di = 0; di < 2; ++di) {
                const int dv = 32 * wc + 16 * di + l15;
                bf[di] = *(const f16x8*)&sVt[dv * 64 + ((32 * ks + 8 * lhi) ^ ((dv & 7) << 3))];
            }
#pragma unroll
            for (int ai = 0; ai < 4; ++ai)
#pragma unroll
                for (int di = 0; di < 2; ++di)
                    acc[ai][di] = __builtin_amdgcn_mfma_f32_16x16x32_f16(af[ai], bf[di], acc[ai][di], 0, 0, 0);
        }
        __syncthreads();
    }

    // ---- per-block partial, stored TRANSPOSED [dv][r] so 4 consecutive r pack
    f16* po = partials + (size_t)blk * (kR * kDV);
#pragma unroll
    for (int ai = 0; ai < 4; ++ai)
#pragma unroll
        for (int di = 0; di < 2; ++di) {
            const int dv = 32 * wc + 16 * di + l15;
            f16x4 pk;
#pragma unroll
            for (int j = 0; j < 4; ++j) pk[j] = (f16)acc[ai][di][j];
            *(f16x4*)&po[dv * kR + 64 * wr + 16 * ai + 4 * lhi] = pk;
        }
}

// ---------------------------------------------------------------------------
// Kernel R: kvT[o] = sum over 512 slices of partials[s][o]   (o = dv*256 + r)
// 32 blocks x 512 thr; wave sums 64 slices over its 512-o stripe, LDS combine.
// ---------------------------------------------------------------------------
__global__ __launch_bounds__(512)
void favor_reduce(const f16* __restrict__ partials, f16* __restrict__ kvT)
{
    __shared__ float sAcc[8][512];
    const int tid  = threadIdx.x;
    const int w    = tid >> 6;
    const int lane = tid & 63;
    const size_t obase = (size_t)blockIdx.x * 512 + lane * 8;

    float a[8] = {0.f, 0.f, 0.f, 0.f, 0.f, 0.f, 0.f, 0.f};
#pragma unroll 8
    for (int i = 0; i < 64; ++i) {
        const int s = w * 64 + i;
        const f16x8 v = *(const f16x8*)&partials[(size_t)s * (kR * kDV) + obase];
#pragma unroll
        for (int j = 0; j < 8; ++j) a[j] += (float)v[j];
    }
#pragma unroll
    for (int j = 0; j < 8; ++j) sAcc[w][lane * 8 + j] = a[j];
    __syncthreads();

    float tot = 0.f;
#pragma unroll
    for (int g = 0; g < 8; ++g) tot += sAcc[g][tid];
    kvT[(size_t)blockIdx.x * 512 + tid] = (f16)tot;
}

// ---------------------------------------------------------------------------
// Kernel B: out = (phi(Q)*2^10)^T @ kv, scaled 2^-20. 1024 blocks, 64 cols.
// ---------------------------------------------------------------------------
__global__ __launch_bounds__(512, 2)
void favor_out(const float* __restrict__ Qg, const float* __restrict__ Wg,
               const f16* __restrict__ kvT, float* __restrict__ outg)
{
    __shared__ f16 sXt[64 * 64];     // Q chunk [l][d]
    __shared__ f16 sPhiT[64 * 256];  // [l][r]
    __shared__ float sRed[8 * 64];

    const int tid  = threadIdx.x;
    const int w    = tid >> 6;
    const int lane = tid & 63;
    const int l15  = lane & 15;
    const int lhi  = lane >> 4;
    const int l0   = blockIdx.x * 64;

    f16x8 wfrag[2][2];
#pragma unroll
    for (int ri = 0; ri < 2; ++ri)
#pragma unroll
        for (int ks = 0; ks < 2; ++ks) {
            const float* p = Wg + (32 * w + 16 * ri + l15) * kD + 32 * ks + 8 * lhi;
            f16x8 v;
#pragma unroll
            for (int j = 0; j < 8; ++j) v[j] = (f16)p[j];
            wfrag[ri][ks] = v;
        }

    const int lfo = w >> 1;
    const int dvh = w & 1;

    // kv B-fragments from kvT[dv][r]
    f16x8 kvf[2][8];
#pragma unroll
    for (int di = 0; di < 2; ++di) {
        const int dv = 32 * dvh + 16 * di + l15;
#pragma unroll
        for (int ks = 0; ks < 8; ++ks)
            kvf[di][ks] = *(const f16x8*)&kvT[dv * kR + 32 * ks + 8 * lhi];
    }

    // ---- stage Q + norms
    {
        const int scol  = lane;
        const int dbase = w * 8;
        float s = 0.f;
        f16x8 hq;
#pragma unroll
        for (int j = 0; j < 8; ++j) {
            const float x = Qg[(dbase + j) * kL + l0 + scol];
            s += x * x;
            hq[j] = (f16)x;
        }
        sRed[w * 64 + scol] = s;
        *(f16x8*)&sXt[scol * 64 + (dbase ^ ((scol & 7) << 3))] = hq;
    }
    __syncthreads();

    float sqv = 0.f;
#pragma unroll
    for (int g = 0; g < 8; ++g) sqv += sRed[g * 64 + lane];
    float sqs[4];
#pragma unroll
    for (int lf = 0; lf < 4; ++lf) sqs[lf] = __shfl(sqv, lf * 16 + l15, 64);

    // ---- z = W @ Q per ri: C[r][l]; phi packs 4 consecutive r -> [l][r]
#pragma unroll
    for (int ri = 0; ri < 2; ++ri) {
        f32x4 z[4];
#pragma unroll
        for (int lf = 0; lf < 4; ++lf) { f32x4 z0 = {0.f, 0.f, 0.f, 0.f}; z[lf] = z0; }
#pragma unroll
        for (int ks = 0; ks < 2; ++ks) {
            f16x8 bfr[4];
#pragma unroll
            for (int lf = 0; lf < 4; ++lf) {
                const int row = 16 * lf + l15;
                bfr[lf] = *(const f16x8*)&sXt[row * 64 + ((32 * ks + 8 * lhi) ^ ((row & 7) << 3))];
            }
#pragma unroll
            for (int lf = 0; lf < 4; ++lf)
                z[lf] = __builtin_amdgcn_mfma_f32_16x16x32_f16(wfrag[ri][ks], bfr[lf], z[lf], 0, 0, 0);
        }
        const int r0 = 32 * w + 16 * ri + 4 * lhi;
#pragma unroll
        for (int lf = 0; lf < 4; ++lf) {
            const int lc = 16 * lf + l15;
            f16x4 ph;
#pragma unroll
            for (int j = 0; j < 4; ++j)
                ph[j] = (f16)(kDnS * __expf(kAc + kBc * z[lf][j] - sqs[lf]));
            *(f16x4*)&sPhiT[lc * 256 + (r0 ^ ((lc & 7) << 3))] = ph;
        }
    }
    __syncthreads();

    // ---- out tile = phiQ^T @ kv
    f32x4 o2[2];
    { f32x4 z0 = {0.f, 0.f, 0.f, 0.f}; o2[0] = z0; o2[1] = z0; }
    const int lrow = 16 * lfo + l15;
#pragma unroll
    for (int ks = 0; ks < 8; ++ks) {
        const f16x8 af = *(const f16x8*)&sPhiT[lrow * 256 + ((32 * ks + 8 * lhi) ^ ((lrow & 7) << 3))];
#pragma unroll
        for (int di = 0; di < 2; ++di)
            o2[di] = __builtin_amdgcn_mfma_f32_16x16x32_f16(af, kvf[di][ks], o2[di], 0, 0, 0);
    }
#pragma unroll
    for (int di = 0; di < 2; ++di)
#pragma unroll
        for (int j = 0; j < 4; ++j) {
            const int ll = 16 * lfo + 4 * lhi + j;
            const int dv = 32 * dvh + 16 * di + l15;
            outg[(size_t)(l0 + ll) * kDV + dv] = o2[di][j] * kOutScale;
        }
}

extern "C" void kernel_launch(void* const* d_in, const int* in_sizes, int n_in,
                              void* d_out, int out_size, void* d_ws, size_t ws_size,
                              hipStream_t stream)
{
    const float* Q = (const float*)d_in[0];
    const float* K = (const float*)d_in[1];
    const float* V = (const float*)d_in[2];
    const float* W = (const float*)d_in[3];
    float* out = (float*)d_out;

    f16* partials = (f16*)d_ws;  // 512 * 16384 f16 = 16 MiB
    f16* kvT = (f16*)((char*)d_ws + (size_t)kABlocks * kR * kDV * sizeof(f16));

    favor_kv<<<kABlocks, 512, 0, stream>>>(K, V, W, partials);
    favor_reduce<<<32, 512, 0, stream>>>(partials, kvT);
    favor_out<<<kBBlocks, 512, 0, stream>>>(Q, W, kvT, out);

    (void)in_sizes; (void)n_in; (void)out_size; (void)ws_size;
}